// Round 8
// baseline (267.331 us; speedup 1.0000x reference)
//
#include <hip/hip_runtime.h>
#include <hip/hip_bf16.h>

// CIN round 8: TLP + load-under-softmax.
//  - 256-thr blocks, wave owns a fi-class (25 or 10 fi) x 4 j-tiles (64 AGPR acc)
//  - f0 rows remapped so packed softmax u32s ARE the 32x32x16 A-frags (no shfl/cndmask)
//  - all 12 B-frag loads issued BEFORE softmax (latency hides under ~300cyc VALU)
//  - grid: L0 512 = 256b x 2jh; L1 1024 = 256b x 2jh x 2fih, XCD-clustered mapping
//  - xk/xv in LDS (imm-offset ds_read, 2-way free), res f32 (no atomics in L0)
// frag maps (validated R5-R7 in-situ): A[l&31][8*(l>>5)+i], B[8*(l>>5)+i][l&31],
// D: col=l&31, row=(r&3)+8*(r>>2)+4*(l>>5)

#define NF0 40
#define NJ  200

typedef short bf16x8 __attribute__((ext_vector_type(8)));
typedef float f32x16 __attribute__((ext_vector_type(16)));
typedef unsigned short u16;
typedef unsigned int   u32;

static __device__ __forceinline__ u16 f2bf(float f) {
    __hip_bfloat16 h = __float2bfloat16(f);
    return *reinterpret_cast<u16*>(&h);
}

// ---- pack: cw [f0*FI+fi, 200] -> bp frag-major, c'' = fi*48 + f0 (48-pad) ----
// bp[((nt*G + fi*3 + g)*64 + l)*8 + i] = B[c''=fi*48 + g*16+8*(l>>5)+i][j=nt*32+(l&31)]
template<int FI>
__global__ __launch_bounds__(256)
void pack_b(const float* __restrict__ cw, u16* __restrict__ bp) {
    __shared__ u16 s[48][33];
    const int fi = blockIdx.x, nt = blockIdx.y;
    const int t = threadIdx.x;
    for (int idx = t; idx < 48 * 32; idx += 256) {
        int f0 = idx >> 5, jj = idx & 31, j = nt * 32 + jj;
        float v = (f0 < NF0 && j < NJ) ? cw[(size_t)(f0 * FI + fi) * NJ + j] : 0.f;
        s[f0][jj] = f2bf(v);
    }
    __syncthreads();
    if (t < 192) {
        const int g = t >> 6, l = t & 63;
        u16 v[8];
        #pragma unroll
        for (int i = 0; i < 8; ++i) v[i] = s[g * 16 + 8 * (l >> 5) + i][l & 31];
        constexpr int G = FI * 3;
        *reinterpret_cast<bf16x8*>(bp + ((size_t)(nt * G + fi * 3 + g) * 64 + l) * 8)
            = *reinterpret_cast<const bf16x8*>(v);
    }
}

// ---- main layer kernel ----
template<int LAYER>
__global__ __launch_bounds__(256, 3)
void cin_layer(const float* __restrict__ x0,
               const float* __restrict__ wq, const float* __restrict__ wk,
               const float* __restrict__ wv,
               const u16* __restrict__ bp,
               float* __restrict__ res,          // L0: out (f32); L1: in
               float* __restrict__ out)
{
    constexpr int FI   = LAYER ? 200 : 40;
    constexpr int G    = FI * 3;
    constexpr int NFIW = LAYER ? 25 : 10;        // fi per wave (4 waves)

    extern __shared__ float smem[];
    float* s_xk  = smem;                          // [48*32]
    float* s_xv  = smem + 1536;                   // [48*32]
    float* s_o   = smem + 3072;                   // [128]
    float* s_res = smem + 3200;                   // [128*33] (L0 only)

    // XCD-clustered mapping: low 3 bits pick (jh, fih, b-sub) so each XCD's
    // L2 serves one B-quarter.
    const int bid = blockIdx.x;
    const int xx = bid & 7;
    int b, jh, fi0;
    if constexpr (LAYER == 0) {
        jh = xx >> 2; fi0 = 0;
        b = (bid >> 3) * 4 + (xx & 3);
    } else {
        jh = xx >> 2; fi0 = ((xx >> 1) & 1) * 100;
        b = (bid >> 3) + ((xx & 1) << 7);
    }
    const int NT = jh ? 3 : 4;
    const int ntbase = jh * 4;

    const int tid = threadIdx.x;
    const int wid = tid >> 6, lane = tid & 63;
    const int sk = lane & 31, h = lane >> 5;

    if (tid < 128) s_o[tid] = 0.f;
    if constexpr (LAYER == 0)
        for (int i = tid; i < 128 * 33; i += 256) s_res[i] = 0.f;

    // stage xk/xv (rows 40..47 zero-padded)
    for (int i = tid; i < 1536; i += 256) {
        const int r = i >> 5, k = i & 31;
        float xk = 0.f, xv = 0.f;
        if (r < NF0) {
            const float v = x0[(size_t)b * 1280 + r * 32 + k];
            xk = v * wk[r * 32 + k];
            xv = v * wv[r * 32 + k];
        }
        s_xk[i] = xk;
        s_xv[i] = xv;
    }
    __syncthreads();

    const int fw0 = fi0 + wid * NFIW;

    f32x16 acc[4];
    #pragma unroll
    for (int n = 0; n < 4; ++n)
        #pragma unroll
        for (int r = 0; r < 16; ++r) acc[n][r] = 0.f;

    const u16* bb[4];
    #pragma unroll
    for (int n = 0; n < 4; ++n) {
        const int nt = ntbase + ((n < 3) ? n : (NT - 1));   // NT==3 duplicates nt2
        bb[n] = bp + (((size_t)nt * G + fw0 * 3) * 64 + lane) * 8;
    }

    for (int t = 0; t < NFIW; ++t) {
        const int fi = fw0 + t;
        // ---- issue ALL B loads first (12-deep vmcnt pipeline) ----
        bf16x8 v0[4], v1[4], v2[4];
        #pragma unroll
        for (int n = 0; n < 4; ++n) v0[n] = *reinterpret_cast<const bf16x8*>(bb[n]);
        #pragma unroll
        for (int n = 0; n < 4; ++n) v1[n] = *reinterpret_cast<const bf16x8*>(bb[n] + 512);
        #pragma unroll
        for (int n = 0; n < 4; ++n) v2[n] = *reinterpret_cast<const bf16x8*>(bb[n] + 1024);

        // ---- q ----
        float qin;
        if constexpr (LAYER == 0) qin = x0[(size_t)b * 1280 + fi * 32 + sk];
        else                      qin = res[(size_t)b * 6400 + fi * 32 + sk];
        const float q = qin * wq[fi * 32 + sk];

        // ---- softmax (covers the load latency) ----
        // slot m -> row 16*(m>>3) + 8*h + (m&7); h1's rows 40-47 are pads
        float e[24], d = 0.f;
        #pragma unroll
        for (int m = 0; m < 24; ++m) {
            const int row = 16 * (m >> 3) + 8 * h + (m & 7);
            e[m] = __expf(s_xk[row * 32 + sk] * q);
            d += e[m];
        }
        if (h) d -= 8.0f;                 // exclude pads (e=1) from denom
        d += __shfl_xor(d, 32);
        float rcp;
        asm("v_rcp_f32 %0, %1" : "=v"(rcp) : "v"(d));

        u32 pk[12];
        #pragma unroll
        for (int p = 0; p < 12; ++p) {
            const int m0 = (p >> 2) * 8 + (p & 3) * 2;
            const int row0 = 16 * (p >> 2) + 8 * h + (p & 3) * 2;
            const float y0 = e[m0]     * rcp * s_xv[row0 * 32 + sk];
            const float y1 = e[m0 + 1] * rcp * s_xv[(row0 + 1) * 32 + sk];
            pk[p] = (u32)f2bf(y0) | ((u32)f2bf(y1) << 16);
        }
        bf16x8 A0, A1, A2;
        __builtin_memcpy(&A0, &pk[0], 16);
        __builtin_memcpy(&A1, &pk[4], 16);
        __builtin_memcpy(&A2, &pk[8], 16);

        // ---- MFMAs ----
        #pragma unroll
        for (int n = 0; n < 4; ++n)
            acc[n] = __builtin_amdgcn_mfma_f32_32x32x16_bf16(A0, v0[n], acc[n], 0, 0, 0);
        #pragma unroll
        for (int n = 0; n < 4; ++n)
            acc[n] = __builtin_amdgcn_mfma_f32_32x32x16_bf16(A1, v1[n], acc[n], 0, 0, 0);
        #pragma unroll
        for (int n = 0; n < 4; ++n)
            acc[n] = __builtin_amdgcn_mfma_f32_32x32x16_bf16(A2, v2[n], acc[n], 0, 0, 0);

        #pragma unroll
        for (int n = 0; n < 4; ++n) bb[n] += 1536;
    }

    // ---- epilogue ----
    if constexpr (LAYER == 0) {
        // LDS-reduce the 4 waves' fi-partials, then store res (f32) + out[0:200]
        #pragma unroll
        for (int n = 0; n < 4; ++n) {
            if (n < NT) {
                #pragma unroll
                for (int r = 0; r < 16; ++r) {
                    const int k = (r & 3) + 8 * (r >> 2) + 4 * h;
                    atomicAdd(&s_res[(n * 32 + sk) * 33 + k], acc[n][r]);
                }
            }
        }
        __syncthreads();
        for (int i = tid; i < NT * 32 * 32; i += 256) {
            const int jl = i >> 5, k = i & 31;
            const int j = ntbase * 32 + jl;
            if (j < NJ) res[(size_t)b * 6400 + j * 32 + k] = s_res[jl * 33 + k];
        }
        if (tid < NT * 32) {
            const int j = ntbase * 32 + tid;
            if (j < NJ) {
                float s = 0.f;
                #pragma unroll
                for (int k = 0; k < 32; ++k) s += s_res[tid * 33 + k];
                out[(size_t)b * 400 + j] = s;
            }
        }
    } else {
        // per-wave k-sum -> LDS reduce -> one global atomic per element
        #pragma unroll
        for (int n = 0; n < 4; ++n) {
            if (n < NT) {
                float s = 0.f;
                #pragma unroll
                for (int r = 0; r < 16; ++r) s += acc[n][r];
                s += __shfl_xor(s, 32);
                if (h == 0) atomicAdd(&s_o[n * 32 + sk], s);
            }
        }
        __syncthreads();
        if (tid < NT * 32) {
            const int j = ntbase * 32 + tid;
            if (j < NJ) atomicAdd(&out[(size_t)b * 400 + 200 + j], s_o[tid]);
        }
    }
}

extern "C" void kernel_launch(void* const* d_in, const int* in_sizes, int n_in,
                              void* d_out, int out_size, void* d_ws, size_t ws_size,
                              hipStream_t stream) {
    const float* x0  = (const float*)d_in[0];
    const float* wq0 = (const float*)d_in[1];
    const float* wk0 = (const float*)d_in[2];
    const float* wv0 = (const float*)d_in[3];
    const float* cw0 = (const float*)d_in[4];
    const float* wq1 = (const float*)d_in[5];
    const float* wk1 = (const float*)d_in[6];
    const float* wv1 = (const float*)d_in[7];
    const float* cw1 = (const float*)d_in[8];
    float* out = (float*)d_out;

    char* ws = (char*)d_ws;
    float* res = (float*)ws;                       // 256*6400*4 = 6,553,600 B
    u16* bp0 = (u16*)(ws + 6553600);               // 7*120*512*2 =   860,160 B
    u16* bp1 = (u16*)(ws + 6553600 + 860160);      // 7*600*512*2 = 4,300,800 B

    hipMemsetAsync(d_out, 0, (size_t)out_size * 4, stream);

    pack_b<40> <<<dim3(40, 7),  256, 0, stream>>>(cw0, bp0);
    pack_b<200><<<dim3(200, 7), 256, 0, stream>>>(cw1, bp1);

    cin_layer<0><<<512,  256, (3200 + 128 * 33) * 4, stream>>>(
        x0, wq0, wk0, wv0, bp0, res, out);
    cin_layer<1><<<1024, 256, 3200 * 4, stream>>>(
        x0, wq1, wk1, wv1, bp1, res, out);
}

// Round 9
// 205.527 us; speedup vs baseline: 1.3007x; 1.3007x over previous
//
#include <hip/hip_runtime.h>
#include <hip/hip_bf16.h>

// CIN round 9: occupancy-first template. 3 blocks/CU (LDS<=48K, VGPR<=85 via
// launch_bounds(512,6)), exp-recompute softmax (no e[] array), q prefetch,
// M=64 (mt=2) so each B-frag feeds 2 MFMAs. L0 same template, emits
// out[:,0:200] + bf16 res directly.
// frag maps (validated R5-R8 in-situ): A[l&31][8*(l>>5)+i], B[8*(l>>5)+i][l&31],
// D: col=l&31, row=(r&3)+8*(r>>2)+4*(l>>5)

#define NF0 40
#define NJ  200

typedef short bf16x8 __attribute__((ext_vector_type(8)));
typedef float f32x16 __attribute__((ext_vector_type(16)));
typedef unsigned short u16;
typedef unsigned int   u32;
typedef unsigned long long u64;

static __device__ __forceinline__ u16 f2bf(float f) {
    __hip_bfloat16 h = __float2bfloat16(f);
    return *reinterpret_cast<u16*>(&h);
}
static __device__ __forceinline__ float bf2f(u16 u) {
    u32 x = ((u32)u) << 16;
    float f;
    __builtin_memcpy(&f, &x, 4);
    return f;
}

// ---- pack: cw [f0*FI+fi, 200] -> bp frag-major, c'' = fi*48 + f0 (48-pad) ----
// bp[((nt*G + fi*3 + g)*64 + l)*8 + i] = B[c''=fi*48+g*16+8*(l>>5)+i][j=nt*32+(l&31)]
template<int FI>
__global__ __launch_bounds__(256)
void pack_b(const float* __restrict__ cw, u16* __restrict__ bp) {
    __shared__ u16 s[48][33];
    const int fi = blockIdx.x, nt = blockIdx.y;
    const int t = threadIdx.x;
    for (int idx = t; idx < 48 * 32; idx += 256) {
        int f0 = idx >> 5, jj = idx & 31, j = nt * 32 + jj;
        float v = (f0 < NF0 && j < NJ) ? cw[(size_t)(f0 * FI + fi) * NJ + j] : 0.f;
        s[f0][jj] = f2bf(v);
    }
    __syncthreads();
    if (t < 192) {
        const int g = t >> 6, l = t & 63;
        u16 v[8];
        #pragma unroll
        for (int i = 0; i < 8; ++i) v[i] = s[g * 16 + 8 * (l >> 5) + i][l & 31];
        constexpr int G = FI * 3;
        *reinterpret_cast<bf16x8*>(bp + ((size_t)(nt * G + fi * 3 + g) * 64 + l) * 8)
            = *reinterpret_cast<const bf16x8*>(v);
    }
}

// ---- layer 0: grid 512 = 256 b x 2 jh; M=32; chunk = 8 fi, 5 chunks ----
__global__ __launch_bounds__(512, 6)
void cin_l0(const float* __restrict__ x0,
            const float* __restrict__ wq, const float* __restrict__ wk,
            const float* __restrict__ wv,
            const u16* __restrict__ bp,
            u16* __restrict__ resh, float* __restrict__ out) {
    __shared__ float s_xk[48 * 32], s_xv[48 * 32];   // 12 KB
    __shared__ char  s_XT[32 * 768];                 // 24 KB

    const int tid = threadIdx.x;
    const int b = blockIdx.x >> 1, jh = blockIdx.x & 1;
    const int wid = tid >> 6, lane = tid & 63;
    const int k = lane & 31, h = lane >> 5;

    for (int i = tid; i < 32 * 768 / 8; i += 512) ((u64*)s_XT)[i] = 0ull;
    for (int i = tid; i < 1536; i += 512) {
        const int r = i >> 5, kk = i & 31;
        float xk = 0.f, xv = 0.f;
        if (r < NF0) {
            const float v = x0[(size_t)b * 1280 + r * 32 + kk];
            xk = v * wk[r * 32 + kk];
            xv = v * wv[r * 32 + kk];
        }
        s_xk[i] = xk; s_xv[i] = xv;
    }
    __syncthreads();

    const int sfil = wid;                     // fi-local 0..7
    const int soff = sfil * 96 + h * 40;
    const int sswz = (k & 7) << 4;
    char* srb = s_XT + k * 768;

    const int nt = jh * 4 + wid;
    const bool hasnt = jh ? (wid < 3) : (wid < 4);
    const int arow = lane & 31;
    char* apb = s_XT + arow * 768;
    const int aswz = (arow & 7) << 4;
    const int ah = h * 16;

    float qx = x0[(size_t)b * 1280 + sfil * 32 + k];
    float qw = wq[sfil * 32 + k];

    f32x16 acc;
    #pragma unroll
    for (int r = 0; r < 16; ++r) acc[r] = 0.f;

    for (int ch = 0; ch < 5; ++ch) {
        const float q = qx * qw;
        if (ch + 1 < 5) {
            const int fi = (ch + 1) * 8 + sfil;
            qx = x0[(size_t)b * 1280 + fi * 32 + k];
            qw = wq[fi * 32 + k];
        }
        // pass 1: denominator (h halves f0)
        float d = 0.f;
        const int fb = h * 20;
        #pragma unroll
        for (int i = 0; i < 20; ++i) d += __expf(s_xk[(fb + i) * 32 + k] * q);
        d += __shfl_xor(d, 32);
        const float rcp = 1.0f / d;
        // pass 2: recompute exp, scale, pack, store
        #pragma unroll
        for (int p = 0; p < 10; ++p) {
            const int f0 = fb + 2 * p;
            const float y0 = __expf(s_xk[f0 * 32 + k] * q)       * rcp * s_xv[f0 * 32 + k];
            const float y1 = __expf(s_xk[(f0 + 1) * 32 + k] * q) * rcp * s_xv[(f0 + 1) * 32 + k];
            *reinterpret_cast<u32*>(srb + ((soff + p * 4) ^ sswz))
                = (u32)f2bf(y0) | ((u32)f2bf(y1) << 16);
        }
        __syncthreads();
        __builtin_amdgcn_s_setprio(1);
        if (hasnt) {
            #pragma unroll
            for (int ks = 0; ks < 24; ++ks) {
                bf16x8 bv = *reinterpret_cast<const bf16x8*>(
                    bp + ((size_t)(nt * 120 + ch * 24 + ks) * 64 + lane) * 8);
                bf16x8 av = *reinterpret_cast<const bf16x8*>(
                    apb + ((ks * 32 + ah) ^ aswz));
                acc = __builtin_amdgcn_mfma_f32_32x32x16_bf16(av, bv, acc, 0, 0, 0);
            }
        }
        __builtin_amdgcn_s_setprio(0);
        __syncthreads();
    }

    if (hasnt) {
        const int j = nt * 32 + (lane & 31);
        if (j < NJ) {
            u16* dst = resh + (size_t)b * 6400 + j * 32;
            #pragma unroll
            for (int rg = 0; rg < 4; ++rg) {     // k = 8*rg + 4*h + 0..3
                u64 w = (u64)f2bf(acc[4*rg+0]) | ((u64)f2bf(acc[4*rg+1]) << 16)
                      | ((u64)f2bf(acc[4*rg+2]) << 32) | ((u64)f2bf(acc[4*rg+3]) << 48);
                *reinterpret_cast<u64*>(dst + 8 * rg + 4 * h) = w;
            }
            float s = 0.f;
            #pragma unroll
            for (int r = 0; r < 16; ++r) s += acc[r];
            s += __shfl_xor(s, 32);
            if (lane < 32) out[(size_t)b * 400 + j] = s;
        }
    }
}

// ---- layer 1: grid 512 = 128 bg x 4 splits; M=64 (2 batches); chunk = 4 fi ----
__global__ __launch_bounds__(512, 6)
void cin_l1(const float* __restrict__ x0, const u16* __restrict__ resh,
            const float* __restrict__ wq, const float* __restrict__ wk,
            const float* __restrict__ wv,
            const u16* __restrict__ bp, float* __restrict__ out) {
    __shared__ float s_xk[2 * 48 * 32], s_xv[2 * 48 * 32];  // 24 KB
    __shared__ char  s_XT[64 * 384];                        // 24 KB

    const int tid = threadIdx.x;
    const int bg = blockIdx.x >> 2, split = blockIdx.x & 3;
    const int b0 = bg * 2;
    const int fbase = split * 52;
    const int nch = (split == 3) ? 11 : 13;
    const int wid = tid >> 6, lane = tid & 63;
    const int k = lane & 31, h = lane >> 5;

    for (int i = tid; i < 64 * 384 / 8; i += 512) ((u64*)s_XT)[i] = 0ull;
    for (int i = tid; i < 3072; i += 512) {
        const int bb = i / 1536, rr = i - bb * 1536;
        const int r = rr >> 5, kk = rr & 31;
        float xk = 0.f, xv = 0.f;
        if (r < NF0) {
            const float v = x0[(size_t)(b0 + bb) * 1280 + r * 32 + kk];
            xk = v * wk[r * 32 + kk];
            xv = v * wv[r * 32 + kk];
        }
        s_xk[i] = xk; s_xv[i] = xv;
    }
    __syncthreads();

    const int sbb = tid >> 8, sfil = (tid >> 6) & 3;
    const int srow = sbb * 32 + k;
    const int soff = sfil * 96 + h * 40;
    const int sswz = (srow & 7) << 4;
    char* srb = s_XT + srow * 384;
    const float* xkp = s_xk + sbb * 1536;
    const float* xvp = s_xv + sbb * 1536;

    const int nt = wid;
    const bool hasnt = (wid < 7);
    const int arow = lane & 31;
    const int ah = h * 16;

    u16   qr = resh[(size_t)(b0 + sbb) * 6400 + (fbase + sfil) * 32 + k];
    float qw = wq[(fbase + sfil) * 32 + k];

    f32x16 acc0, acc1;
    #pragma unroll
    for (int r = 0; r < 16; ++r) { acc0[r] = 0.f; acc1[r] = 0.f; }

    for (int ch = 0; ch < nch; ++ch) {
        const float q = bf2f(qr) * qw;
        if (ch + 1 < nch) {
            const int fi = fbase + (ch + 1) * 4 + sfil;
            qr = resh[(size_t)(b0 + sbb) * 6400 + fi * 32 + k];
            qw = wq[fi * 32 + k];
        }
        float d = 0.f;
        const int fb = h * 20;
        #pragma unroll
        for (int i = 0; i < 20; ++i) d += __expf(xkp[(fb + i) * 32 + k] * q);
        d += __shfl_xor(d, 32);
        const float rcp = 1.0f / d;
        #pragma unroll
        for (int p = 0; p < 10; ++p) {
            const int f0 = fb + 2 * p;
            const float y0 = __expf(xkp[f0 * 32 + k] * q)       * rcp * xvp[f0 * 32 + k];
            const float y1 = __expf(xkp[(f0 + 1) * 32 + k] * q) * rcp * xvp[(f0 + 1) * 32 + k];
            *reinterpret_cast<u32*>(srb + ((soff + p * 4) ^ sswz))
                = (u32)f2bf(y0) | ((u32)f2bf(y1) << 16);
        }
        __syncthreads();
        __builtin_amdgcn_s_setprio(1);
        if (hasnt) {
            const int gbase = fbase * 3 + ch * 12;
            #pragma unroll
            for (int ks = 0; ks < 12; ++ks) {
                bf16x8 bv = *reinterpret_cast<const bf16x8*>(
                    bp + ((size_t)(nt * 600 + gbase + ks) * 64 + lane) * 8);
                const int cb = ks * 32 + ah;
                bf16x8 a0 = *reinterpret_cast<const bf16x8*>(
                    s_XT + arow * 384 + (cb ^ ((arow & 7) << 4)));
                const int brow = 32 + arow;
                bf16x8 a1 = *reinterpret_cast<const bf16x8*>(
                    s_XT + brow * 384 + (cb ^ ((brow & 7) << 4)));
                acc0 = __builtin_amdgcn_mfma_f32_32x32x16_bf16(a0, bv, acc0, 0, 0, 0);
                acc1 = __builtin_amdgcn_mfma_f32_32x32x16_bf16(a1, bv, acc1, 0, 0, 0);
            }
        }
        __builtin_amdgcn_s_setprio(0);
        __syncthreads();
    }

    if (hasnt) {
        const int j = nt * 32 + (lane & 31);
        float s0 = 0.f, s1 = 0.f;
        #pragma unroll
        for (int r = 0; r < 16; ++r) { s0 += acc0[r]; s1 += acc1[r]; }
        s0 += __shfl_xor(s0, 32);
        s1 += __shfl_xor(s1, 32);
        if (lane < 32 && j < NJ) {
            atomicAdd(&out[(size_t)b0 * 400 + 200 + j], s0);
            atomicAdd(&out[(size_t)(b0 + 1) * 400 + 200 + j], s1);
        }
    }
}

extern "C" void kernel_launch(void* const* d_in, const int* in_sizes, int n_in,
                              void* d_out, int out_size, void* d_ws, size_t ws_size,
                              hipStream_t stream) {
    const float* x0  = (const float*)d_in[0];
    const float* wq0 = (const float*)d_in[1];
    const float* wk0 = (const float*)d_in[2];
    const float* wv0 = (const float*)d_in[3];
    const float* cw0 = (const float*)d_in[4];
    const float* wq1 = (const float*)d_in[5];
    const float* wk1 = (const float*)d_in[6];
    const float* wv1 = (const float*)d_in[7];
    const float* cw1 = (const float*)d_in[8];
    float* out = (float*)d_out;

    char* ws = (char*)d_ws;
    u16* resh = (u16*)ws;                         // 256*6400*2 = 3,276,800 B
    u16* bp0  = (u16*)(ws + 3276800);             // 7*120*512*2 =   860,160 B
    u16* bp1  = (u16*)(ws + 3276800 + 860160);    // 7*600*512*2 = 4,300,800 B

    hipMemsetAsync(d_out, 0, (size_t)out_size * 4, stream);

    pack_b<40> <<<dim3(40, 7),  256, 0, stream>>>(cw0, bp0);
    pack_b<200><<<dim3(200, 7), 256, 0, stream>>>(cw1, bp1);

    cin_l0<<<512, 512, 0, stream>>>(x0, wq0, wk0, wv0, bp0, resh, out);
    cin_l1<<<512, 512, 0, stream>>>(x0, resh, wq1, wk1, wv1, bp1, out);
}